// Round 3
// baseline (3262.317 us; speedup 1.0000x reference)
//
#include <hip/hip_runtime.h>
#include <cstdint>

typedef _Float16 f16;
typedef _Float16 f16x4v __attribute__((ext_vector_type(4)));
typedef _Float16 f16x8 __attribute__((ext_vector_type(8)));
typedef float f32x4 __attribute__((ext_vector_type(4)));

#define DEV static __device__ __forceinline__

// async global->LDS, 16B per lane; LDS dest = wave-uniform base + lane*16
#define GLDS16(gp, lp) __builtin_amdgcn_global_load_lds( \
    (const __attribute__((address_space(1))) void*)(gp), \
    (__attribute__((address_space(3))) void*)(lp), 16, 0, 0)

DEV float sigf(float x) { return 1.0f / (1.0f + __expf(-x)); }
DEV float tanh2(float x) {
  float e = __expf(-2.0f * fabsf(x));
  float t = (1.0f - e) / (1.0f + e);
  return x >= 0.0f ? t : -t;
}

// ---------------- fp32 -> fp16 convert (n % 4 == 0) ----------------
__global__ __launch_bounds__(256) void k_cvt(const float* __restrict__ s,
                                             f16* __restrict__ d, int n) {
  int i = (blockIdx.x * 256 + threadIdx.x) * 4;
  if (i >= n) return;
  float4 v = *(const float4*)(s + i);
  f16x4v o;
  o.x = (f16)v.x; o.y = (f16)v.y; o.z = (f16)v.z; o.w = (f16)v.w;
  *(f16x4v*)(d + i) = o;
}

// ---------------- pack Whh (4096x1024 fp32) into MFMA fragment order -------
// frag = (ut*4+gate)*32 + kt ; lane l holds 8 halves =
// W[gate*1024 + ut*16 + (l&15)][kt*32 + 8*(l>>4) + j]
__global__ __launch_bounds__(256) void k_packw1(const float* __restrict__ W,
                                                f16* __restrict__ P) {
  int i2 = blockIdx.x * 256 + threadIdx.x;   // 0 .. 524287
  int l = i2 & 63, frag = i2 >> 6;
  int kt = frag & 31, ug = frag >> 5;
  int gate = ug & 3, ut = ug >> 2;
  int row = gate * 1024 + ut * 16 + (l & 15);
  int k = kt * 32 + 8 * (l >> 4);
  const float* s = W + row * 1024 + k;
  f16x8 o;
#pragma unroll
  for (int j = 0; j < 8; ++j) o[j] = (f16)s[j];
  *(f16x8*)(P + frag * 512 + l * 8) = o;
}

// ---------------- big GEMM: C = A @ B^T + (bi+bh), fp16 out ----------------
// A (2048 x LDA), B (4096 x LDA) row-major k-contiguous. 128x128 tile,
// BK=64, 4 waves each 64x64 (m97 structure, global_load_lds width 16).
template <int NKT, int LDA>
__global__ __launch_bounds__(256) void k_igemm(
    const f16* __restrict__ A0, const f16* __restrict__ A1,
    const f16* __restrict__ B0, const f16* __restrict__ B1,
    const float* __restrict__ bi0, const float* __restrict__ bh0,
    const float* __restrict__ bi1, const float* __restrict__ bh1,
    f16* __restrict__ C0, f16* __restrict__ C1) {
  const f16* A = blockIdx.z ? A1 : A0;
  const f16* B = blockIdx.z ? B1 : B0;
  const float* bi = blockIdx.z ? bi1 : bi0;
  const float* bh = blockIdx.z ? bh1 : bh0;
  f16* C = blockIdx.z ? C1 : C0;

  __shared__ alignas(16) f16 As[128 * 64];
  __shared__ alignas(16) f16 Bs[128 * 64];

  int tid = threadIdx.x, l = tid & 63, w = tid >> 6;
  int m0 = blockIdx.x * 128, n0 = blockIdx.y * 128;
  int wm = (w & 1) * 64, wn = (w >> 1) * 64;
  int lr = l & 15, lg = l >> 4;
  int sr = w * 32 + (l >> 3);
  int sc = (l & 7) * 8;

  f32x4 acc[4][4];
  f32x4 zero = {0.f, 0.f, 0.f, 0.f};
#pragma unroll
  for (int mt = 0; mt < 4; ++mt)
#pragma unroll
    for (int nt = 0; nt < 4; ++nt) acc[mt][nt] = zero;

  for (int kt = 0; kt < NKT; ++kt) {
    int k0 = kt * 64;
#pragma unroll
    for (int c2 = 0; c2 < 4; ++c2) {
      GLDS16(A + (size_t)(m0 + sr + c2 * 8) * LDA + k0 + sc, &As[(w * 32 + c2 * 8) * 64]);
      GLDS16(B + (size_t)(n0 + sr + c2 * 8) * LDA + k0 + sc, &Bs[(w * 32 + c2 * 8) * 64]);
    }
    __syncthreads();
#pragma unroll
    for (int ks = 0; ks < 2; ++ks) {
      f16x8 af[4], bf[4];
#pragma unroll
      for (int mt = 0; mt < 4; ++mt)
        af[mt] = *(const f16x8*)&As[(wm + mt * 16 + lr) * 64 + ks * 32 + 8 * lg];
#pragma unroll
      for (int nt = 0; nt < 4; ++nt)
        bf[nt] = *(const f16x8*)&Bs[(wn + nt * 16 + lr) * 64 + ks * 32 + 8 * lg];
#pragma unroll
      for (int mt = 0; mt < 4; ++mt)
#pragma unroll
        for (int nt = 0; nt < 4; ++nt)
          acc[mt][nt] = __builtin_amdgcn_mfma_f32_16x16x32_f16(af[mt], bf[nt], acc[mt][nt], 0, 0, 0);
    }
    __syncthreads();
  }

#pragma unroll
  for (int nt = 0; nt < 4; ++nt) {
    int n = n0 + wn + nt * 16 + lr;
    float bsum = bi[n] + bh[n];
#pragma unroll
    for (int mt = 0; mt < 4; ++mt) {
      int m = m0 + wm + mt * 16 + lg * 4;
#pragma unroll
      for (int r = 0; r < 4; ++r)
        C[(size_t)(m + r) * 4096 + n] = (f16)(acc[mt][nt][r] + bsum);
    }
  }
}

// ---------------- persistent scan with manual grid barrier ------------------
// One LSTM-cell recurrence, 64 steps. 128 blocks = 2 streams x 64 unit-groups
// (16 units each), all co-resident (128 <= 256 CUs, 1 block/CU feasible).
// Weights (own 64 gate-rows x K=1024) live in VGPRs. Per step: G t-slice
// prefetch, 64 MFMAs (4 waves split K), LDS reduce, wave0 LSTM epilogue with
// c in registers, then flag-array barrier with explicit release/acquire.
__global__ __launch_bounds__(256, 1) void k_scan(
    const f16* __restrict__ Wp_a, const f16* __restrict__ Wp_m,
    const f16* __restrict__ G_a, const f16* __restrict__ G_m,
    f16* __restrict__ hping,          // 2 x 2 x 32 x 1024, zeroed
    f16* __restrict__ aux_a, f16* __restrict__ aux_m, int aux_ld,
    unsigned* __restrict__ flags) {   // 128 uints, zeroed
  int bi = blockIdx.x;
  int s = bi >> 6, ut = bi & 63, u0 = ut * 16;
  const f16* Wp = s ? Wp_m : Wp_a;
  const f16* G = s ? G_m : G_a;
  f16* aux = s ? aux_m : aux_a;
  int tid = threadIdx.x, l = tid & 63, w = tid >> 6;
  int lr = l & 15, lg = l >> 4;

  // this wave's weight fragments -> registers (held for all 64 steps)
  f16x8 wreg[8][4];
#pragma unroll
  for (int ks = 0; ks < 8; ++ks)
#pragma unroll
    for (int g = 0; g < 4; ++g)
      wreg[ks][g] = *(const f16x8*)(Wp + (size_t)((ut * 4 + g) * 32 + (w * 8 + ks)) * 512 + l * 8);

  __shared__ alignas(16) float red[3][64][32];
  __shared__ alignas(16) f16 Gs[32][4][16];

  int pb = tid >> 3, pg = (tid >> 1) & 3, ph = tid & 1;  // G prefetch mapping

  float creg[2][4];
#pragma unroll
  for (int mt = 0; mt < 2; ++mt)
#pragma unroll
    for (int r = 0; r < 4; ++r) creg[mt][r] = 0.f;

  const int S = 2 * 32 * 1024;
  for (int t = 0; t < 64; ++t) {
    const f16* hprev = hping + (t & 1) * S + s * (32 * 1024);
    f16* hnext = hping + ((t & 1) ^ 1) * S + s * (32 * 1024);

    // issue G t-slice load early; consumed after the MFMA phase (T14)
    f16x8 gfrag = *(const f16x8*)(G + (size_t)(pb * 64 + t) * 4096 + pg * 1024 + u0 + ph * 8);

    f32x4 acc[2][4];
    f32x4 zero = {0.f, 0.f, 0.f, 0.f};
#pragma unroll
    for (int mt = 0; mt < 2; ++mt)
#pragma unroll
      for (int g = 0; g < 4; ++g) acc[mt][g] = zero;

    int kw = w * 256;
#pragma unroll
    for (int ks = 0; ks < 8; ++ks) {
      int kk = kw + ks * 32;
      f16x8 a0 = *(const f16x8*)(hprev + lr * 1024 + kk + 8 * lg);
      f16x8 a1 = *(const f16x8*)(hprev + (16 + lr) * 1024 + kk + 8 * lg);
#pragma unroll
      for (int g = 0; g < 4; ++g) {
        acc[0][g] = __builtin_amdgcn_mfma_f32_16x16x32_f16(a0, wreg[ks][g], acc[0][g], 0, 0, 0);
        acc[1][g] = __builtin_amdgcn_mfma_f32_16x16x32_f16(a1, wreg[ks][g], acc[1][g], 0, 0, 0);
      }
    }

    *(f16x8*)&Gs[pb][pg][ph * 8] = gfrag;
    if (w) {
#pragma unroll
      for (int mt = 0; mt < 2; ++mt)
#pragma unroll
        for (int g = 0; g < 4; ++g)
#pragma unroll
          for (int r = 0; r < 4; ++r)
            red[w - 1][l][(mt * 4 + g) * 4 + r] = acc[mt][g][r];
    }
    __syncthreads();
    if (w == 0) {
#pragma unroll
      for (int mt = 0; mt < 2; ++mt)
#pragma unroll
        for (int g = 0; g < 4; ++g)
#pragma unroll
          for (int r = 0; r < 4; ++r) {
            int idx = (mt * 4 + g) * 4 + r;
            acc[mt][g][r] += red[0][l][idx] + red[1][l][idx] + red[2][l][idx];
          }
      int u = u0 + lr;
#pragma unroll
      for (int mt = 0; mt < 2; ++mt) {
#pragma unroll
        for (int r = 0; r < 4; ++r) {
          int b_ = mt * 16 + lg * 4 + r;
          float pi = acc[mt][0][r] + (float)Gs[b_][0][lr];
          float pf = acc[mt][1][r] + (float)Gs[b_][1][lr];
          float pg_ = acc[mt][2][r] + (float)Gs[b_][2][lr];
          float po = acc[mt][3][r] + (float)Gs[b_][3][lr];
          float cn = sigf(pf) * creg[mt][r] + sigf(pi) * tanh2(pg_);
          creg[mt][r] = cn;
          f16 hv = (f16)(sigf(po) * tanh2(cn));
          hnext[b_ * 1024 + u] = hv;
          aux[(size_t)(b_ * 64 + t) * aux_ld + u] = hv;
        }
      }
    }

    if (t < 63) {
      // ---- grid barrier: release, arrive, poll, acquire ----
      __threadfence();  // wave0's h/aux stores -> agent-visible (release)
      if (tid == 0)
        __hip_atomic_store(&flags[bi], (unsigned)(t + 1), __ATOMIC_RELEASE,
                           __HIP_MEMORY_SCOPE_AGENT);
      if (w == 0) {
        unsigned want = (unsigned)(t + 1);
        while (__hip_atomic_load(&flags[l], __ATOMIC_RELAXED,
                                 __HIP_MEMORY_SCOPE_AGENT) < want ||
               __hip_atomic_load(&flags[64 + l], __ATOMIC_RELAXED,
                                 __HIP_MEMORY_SCOPE_AGENT) < want) {
        }
      }
      __syncthreads();
      __threadfence();  // acquire: invalidate local caches before next reads
    }
  }
}

// ---------------- fusion: one GEMM phase helper -----------------------------
DEV void gemm_phase(const f16* __restrict__ H, int kA0,
                    const f16* __restrict__ Bp, int brs, int nk,
                    f16* As, f16* Bs, int m0, int n0, int w, int l,
                    int wm, int wn, f32x4 (&acc)[4][2]) {
  f32x4 zero = {0.f, 0.f, 0.f, 0.f};
#pragma unroll
  for (int mt = 0; mt < 4; ++mt)
#pragma unroll
    for (int nt = 0; nt < 2; ++nt) acc[mt][nt] = zero;
  int lr = l & 15, lg = l >> 4;
  int sc = (l & 7) * 8;
  for (int kt = 0; kt < nk; ++kt) {
    int ka = kA0 + kt * 64, kb = kt * 64;
#pragma unroll
    for (int c2 = 0; c2 < 4; ++c2)
      GLDS16(H + (size_t)(m0 + w * 32 + c2 * 8 + (l >> 3)) * 2048 + ka + sc,
             As + (w * 32 + c2 * 8) * 64);
#pragma unroll
    for (int c2 = 0; c2 < 2; ++c2)
      GLDS16(Bp + (size_t)(n0 + w * 16 + c2 * 8 + (l >> 3)) * brs + kb + sc,
             Bs + (w * 16 + c2 * 8) * 64);
    __syncthreads();
#pragma unroll
    for (int ks = 0; ks < 2; ++ks) {
      f16x8 af[4], bf[2];
#pragma unroll
      for (int mt = 0; mt < 4; ++mt)
        af[mt] = *(const f16x8*)&As[(wm + mt * 16 + lr) * 64 + ks * 32 + 8 * lg];
#pragma unroll
      for (int nt = 0; nt < 2; ++nt)
        bf[nt] = *(const f16x8*)&Bs[(wn + nt * 16 + lr) * 64 + ks * 32 + 8 * lg];
#pragma unroll
      for (int mt = 0; mt < 4; ++mt)
#pragma unroll
        for (int nt = 0; nt < 2; ++nt)
          acc[mt][nt] = __builtin_amdgcn_mfma_f32_16x16x32_f16(af[mt], bf[nt], acc[mt][nt], 0, 0, 0);
    }
    __syncthreads();
  }
}

// mem = tm + sig(G)*(ta - tm); 128x64 tile per block, 4 waves of 64x32
__global__ __launch_bounds__(256) void k_fusion(
    const f16* __restrict__ H, const f16* __restrict__ Wg16,
    const f16* __restrict__ Wa16, const f16* __restrict__ Wm16,
    const float* __restrict__ bg, const float* __restrict__ ba,
    const float* __restrict__ bm, float* __restrict__ out) {
  __shared__ alignas(16) f16 As[128 * 64];
  __shared__ alignas(16) f16 Bs[64 * 64];
  int tid = threadIdx.x, l = tid & 63, w = tid >> 6;
  int m0 = blockIdx.x * 128, n0 = blockIdx.y * 64;
  int wm = (w & 1) * 64, wn = (w >> 1) * 32;
  int lr = l & 15, lg = l >> 4;

  f32x4 acc[4][2];
  float ta[4][2][4], tm[4][2][4];

  gemm_phase(H, 0, Wa16, 1024, 16, As, Bs, m0, n0, w, l, wm, wn, acc);
#pragma unroll
  for (int nt = 0; nt < 2; ++nt) {
    float bv = ba[n0 + wn + nt * 16 + lr];
#pragma unroll
    for (int mt = 0; mt < 4; ++mt)
#pragma unroll
      for (int r = 0; r < 4; ++r) ta[mt][nt][r] = tanh2(acc[mt][nt][r] + bv);
  }
  gemm_phase(H, 1024, Wm16, 1024, 16, As, Bs, m0, n0, w, l, wm, wn, acc);
#pragma unroll
  for (int nt = 0; nt < 2; ++nt) {
    float bv = bm[n0 + wn + nt * 16 + lr];
#pragma unroll
    for (int mt = 0; mt < 4; ++mt)
#pragma unroll
      for (int r = 0; r < 4; ++r) tm[mt][nt][r] = tanh2(acc[mt][nt][r] + bv);
  }
  gemm_phase(H, 0, Wg16, 2048, 32, As, Bs, m0, n0, w, l, wm, wn, acc);
#pragma unroll
  for (int nt = 0; nt < 2; ++nt) {
    int n = n0 + wn + nt * 16 + lr;
    float bv = bg[n];
#pragma unroll
    for (int mt = 0; mt < 4; ++mt) {
      int m = m0 + wm + mt * 16 + lg * 4;
#pragma unroll
      for (int r = 0; r < 4; ++r) {
        float g = sigf(acc[mt][nt][r] + bv);
        out[(size_t)(m + r) * 1024 + n] = tm[mt][nt][r] + g * (ta[mt][nt][r] - tm[mt][nt][r]);
      }
    }
  }
}

// ===========================================================================
extern "C" void kernel_launch(void* const* d_in, const int* in_sizes, int n_in,
                              void* d_out, int out_size, void* d_ws, size_t ws_size,
                              hipStream_t stream) {
  const float* xa = (const float*)d_in[0];
  const float* xm = (const float*)d_in[1];
  const float* Wih_1a = (const float*)d_in[2];
  const float* Whh_1a = (const float*)d_in[3];
  const float* bih_1a = (const float*)d_in[4];
  const float* bhh_1a = (const float*)d_in[5];
  const float* Wih_2a = (const float*)d_in[6];
  const float* Whh_2a = (const float*)d_in[7];
  const float* bih_2a = (const float*)d_in[8];
  const float* bhh_2a = (const float*)d_in[9];
  const float* Wih_1m = (const float*)d_in[10];
  const float* Whh_1m = (const float*)d_in[11];
  const float* bih_1m = (const float*)d_in[12];
  const float* bhh_1m = (const float*)d_in[13];
  const float* Wih_2m = (const float*)d_in[14];
  const float* Whh_2m = (const float*)d_in[15];
  const float* bih_2m = (const float*)d_in[16];
  const float* bhh_2m = (const float*)d_in[17];
  const float* Wg = (const float*)d_in[18];
  const float* bg = (const float*)d_in[19];
  const float* Wa = (const float*)d_in[20];
  const float* ba = (const float*)d_in[21];
  const float* Wm = (const float*)d_in[22];
  const float* bm = (const float*)d_in[23];

  char* ws = (char*)d_ws;
  const size_t MB = 1024ull * 1024;
  if (ws_size < 138 * MB) return;  // fail visibly

  // fixed layout (with aliasing; offsets in MB)
  f16* x16a    = (f16*)(ws + 0 * MB);     // dead after GEMM A
  f16* x16m    = (f16*)(ws + 8 * MB);     // dead after GEMM A
  f16* W1ih16a = (f16*)(ws + 16 * MB);    // dead after GEMM A
  f16* W1ih16m = (f16*)(ws + 32 * MB);    // dead after GEMM A
  f16* W2ih16a = (f16*)(ws + 48 * MB);
  f16* W2ih16m = (f16*)(ws + 56 * MB);
  f16* W1p_a   = (f16*)(ws + 64 * MB);
  f16* W1p_m   = (f16*)(ws + 72 * MB);
  f16* W2p_a   = (f16*)(ws + 80 * MB);
  f16* W2p_m   = (f16*)(ws + 88 * MB);
  f16* Wg16    = (f16*)(ws + 96 * MB);
  f16* Wa16    = (f16*)(ws + 100 * MB);
  f16* Wm16    = (f16*)(ws + 102 * MB);
  f16* G0a     = (f16*)(ws + 104 * MB);
  f16* G0m     = (f16*)(ws + 120 * MB);
  f16* hbufA   = (f16*)(ws + 136 * MB);   // 256 KB
  f16* hbufB   = (f16*)(ws + 136 * MB + 256 * 1024);
  unsigned* flagsA = (unsigned*)(ws + 137 * MB);          // 512 B
  unsigned* flagsB = (unsigned*)(ws + 137 * MB + 512);    // 512 B
  // aliases over GEMM-A-dead regions:
  f16* G1a  = (f16*)(ws + 0 * MB);        // 16 MB over x16a+x16m
  f16* G1m  = (f16*)(ws + 16 * MB);       // 16 MB over W1ih16a
  f16* HaHm = (f16*)(ws + 32 * MB);       // 8 MB over W1ih16m[0:8]
  f16* H1a  = (f16*)(ws + 40 * MB);       // 4 MB over W1ih16m[8:12]
  f16* H1m  = (f16*)(ws + 44 * MB);       // 4 MB over W1ih16m[12:16]

  dim3 B256(256);
  k_cvt<<<4096, B256, 0, stream>>>(xa, x16a, 4194304);
  k_cvt<<<4096, B256, 0, stream>>>(xm, x16m, 4194304);
  k_cvt<<<8192, B256, 0, stream>>>(Wih_1a, W1ih16a, 8388608);
  k_cvt<<<8192, B256, 0, stream>>>(Wih_1m, W1ih16m, 8388608);
  k_cvt<<<4096, B256, 0, stream>>>(Wih_2a, W2ih16a, 4194304);
  k_cvt<<<4096, B256, 0, stream>>>(Wih_2m, W2ih16m, 4194304);
  k_cvt<<<2048, B256, 0, stream>>>(Wg, Wg16, 2097152);
  k_cvt<<<1024, B256, 0, stream>>>(Wa, Wa16, 1048576);
  k_cvt<<<1024, B256, 0, stream>>>(Wm, Wm16, 1048576);
  k_packw1<<<2048, B256, 0, stream>>>(Whh_1a, W1p_a);
  k_packw1<<<2048, B256, 0, stream>>>(Whh_1m, W1p_m);
  k_packw1<<<2048, B256, 0, stream>>>(Whh_2a, W2p_a);
  k_packw1<<<2048, B256, 0, stream>>>(Whh_2m, W2p_m);
  hipMemsetAsync(hbufA, 0, 512 * 1024, stream);  // hbufA + hbufB
  hipMemsetAsync(flagsA, 0, 1024, stream);       // flagsA + flagsB

  // GEMM A: G0 = x @ Wih_1^T + (bih_1 + bhh_1)
  k_igemm<32, 2048><<<dim3(16, 32, 2), B256, 0, stream>>>(
      x16a, x16m, W1ih16a, W1ih16m, bih_1a, bhh_1a, bih_1m, bhh_1m, G0a, G0m);

  // persistent scan A: h1 chain -> H1
  k_scan<<<128, B256, 0, stream>>>(W1p_a, W1p_m, G0a, G0m, hbufA, H1a, H1m,
                                   1024, flagsA);

  // GEMM B: G1 = H1 @ Wih_2^T + (bih_2 + bhh_2)
  k_igemm<16, 1024><<<dim3(16, 32, 2), B256, 0, stream>>>(
      H1a, H1m, W2ih16a, W2ih16m, bih_2a, bhh_2a, bih_2m, bhh_2m, G1a, G1m);

  // persistent scan B: h2 chain -> HaHm (a in cols [0,1024), m in [1024,2048))
  k_scan<<<128, B256, 0, stream>>>(W2p_a, W2p_m, G1a, G1m, hbufB, HaHm,
                                   HaHm + 1024, 2048, flagsB);

  k_fusion<<<dim3(16, 16), B256, 0, stream>>>(HaHm, Wg16, Wa16, Wm16, bg, ba,
                                              bm, (float*)d_out);
}

// Round 4
// 1758.330 us; speedup vs baseline: 1.8553x; 1.8553x over previous
//
#include <hip/hip_runtime.h>
#include <cstdint>

typedef _Float16 f16;
typedef _Float16 f16x4v __attribute__((ext_vector_type(4)));
typedef _Float16 f16x8 __attribute__((ext_vector_type(8)));
typedef float f32x4 __attribute__((ext_vector_type(4)));

#define DEV static __device__ __forceinline__

// async global->LDS, 16B per lane; LDS dest = wave-uniform base + lane*16
#define GLDS16(gp, lp) __builtin_amdgcn_global_load_lds( \
    (const __attribute__((address_space(1))) void*)(gp), \
    (__attribute__((address_space(3))) void*)(lp), 16, 0, 0)

DEV float sigf(float x) { return 1.0f / (1.0f + __expf(-x)); }
DEV float tanh2(float x) {
  float e = __expf(-2.0f * fabsf(x));
  float t = (1.0f - e) / (1.0f + e);
  return x >= 0.0f ? t : -t;
}

// coherent (agent-scope, sc0 sc1) 16B load as 4 relaxed dword atomics:
// bypasses potentially-stale L1/L2, reads L3 coherence point, no cache inv.
DEV f16x8 ld_coh16(const f16* p) {
  const unsigned* q = (const unsigned*)p;
  union { unsigned u[4]; f16x8 v; } cv;
#pragma unroll
  for (int i = 0; i < 4; ++i)
    cv.u[i] = __hip_atomic_load(q + i, __ATOMIC_RELAXED, __HIP_MEMORY_SCOPE_AGENT);
  return cv.v;
}

// ---------------- fp32 -> fp16 convert (n % 4 == 0) ----------------
__global__ __launch_bounds__(256) void k_cvt(const float* __restrict__ s,
                                             f16* __restrict__ d, int n) {
  int i = (blockIdx.x * 256 + threadIdx.x) * 4;
  if (i >= n) return;
  float4 v = *(const float4*)(s + i);
  f16x4v o;
  o.x = (f16)v.x; o.y = (f16)v.y; o.z = (f16)v.z; o.w = (f16)v.w;
  *(f16x4v*)(d + i) = o;
}

// ---------------- pack Whh (4096x1024 fp32) into MFMA fragment order -------
// frag = (ut*4+gate)*32 + kt ; lane l holds 8 halves =
// W[gate*1024 + ut*16 + (l&15)][kt*32 + 8*(l>>4) + j]
__global__ __launch_bounds__(256) void k_packw1(const float* __restrict__ W,
                                                f16* __restrict__ P) {
  int i2 = blockIdx.x * 256 + threadIdx.x;   // 0 .. 524287
  int l = i2 & 63, frag = i2 >> 6;
  int kt = frag & 31, ug = frag >> 5;
  int gate = ug & 3, ut = ug >> 2;
  int row = gate * 1024 + ut * 16 + (l & 15);
  int k = kt * 32 + 8 * (l >> 4);
  const float* s = W + row * 1024 + k;
  f16x8 o;
#pragma unroll
  for (int j = 0; j < 8; ++j) o[j] = (f16)s[j];
  *(f16x8*)(P + frag * 512 + l * 8) = o;
}

// ---------------- big GEMM: C = A @ B^T + (bi+bh), fp16 out ----------------
template <int NKT, int LDA>
__global__ __launch_bounds__(256) void k_igemm(
    const f16* __restrict__ A0, const f16* __restrict__ A1,
    const f16* __restrict__ B0, const f16* __restrict__ B1,
    const float* __restrict__ bi0, const float* __restrict__ bh0,
    const float* __restrict__ bi1, const float* __restrict__ bh1,
    f16* __restrict__ C0, f16* __restrict__ C1) {
  const f16* A = blockIdx.z ? A1 : A0;
  const f16* B = blockIdx.z ? B1 : B0;
  const float* bi = blockIdx.z ? bi1 : bi0;
  const float* bh = blockIdx.z ? bh1 : bh0;
  f16* C = blockIdx.z ? C1 : C0;

  __shared__ alignas(16) f16 As[128 * 64];
  __shared__ alignas(16) f16 Bs[128 * 64];

  int tid = threadIdx.x, l = tid & 63, w = tid >> 6;
  int m0 = blockIdx.x * 128, n0 = blockIdx.y * 128;
  int wm = (w & 1) * 64, wn = (w >> 1) * 64;
  int lr = l & 15, lg = l >> 4;
  int sr = w * 32 + (l >> 3);
  int sc = (l & 7) * 8;

  f32x4 acc[4][4];
  f32x4 zero = {0.f, 0.f, 0.f, 0.f};
#pragma unroll
  for (int mt = 0; mt < 4; ++mt)
#pragma unroll
    for (int nt = 0; nt < 4; ++nt) acc[mt][nt] = zero;

  for (int kt = 0; kt < NKT; ++kt) {
    int k0 = kt * 64;
#pragma unroll
    for (int c2 = 0; c2 < 4; ++c2) {
      GLDS16(A + (size_t)(m0 + sr + c2 * 8) * LDA + k0 + sc, &As[(w * 32 + c2 * 8) * 64]);
      GLDS16(B + (size_t)(n0 + sr + c2 * 8) * LDA + k0 + sc, &Bs[(w * 32 + c2 * 8) * 64]);
    }
    __syncthreads();
#pragma unroll
    for (int ks = 0; ks < 2; ++ks) {
      f16x8 af[4], bf[4];
#pragma unroll
      for (int mt = 0; mt < 4; ++mt)
        af[mt] = *(const f16x8*)&As[(wm + mt * 16 + lr) * 64 + ks * 32 + 8 * lg];
#pragma unroll
      for (int nt = 0; nt < 4; ++nt)
        bf[nt] = *(const f16x8*)&Bs[(wn + nt * 16 + lr) * 64 + ks * 32 + 8 * lg];
#pragma unroll
      for (int mt = 0; mt < 4; ++mt)
#pragma unroll
        for (int nt = 0; nt < 4; ++nt)
          acc[mt][nt] = __builtin_amdgcn_mfma_f32_16x16x32_f16(af[mt], bf[nt], acc[mt][nt], 0, 0, 0);
    }
    __syncthreads();
  }

#pragma unroll
  for (int nt = 0; nt < 4; ++nt) {
    int n = n0 + wn + nt * 16 + lr;
    float bsum = bi[n] + bh[n];
#pragma unroll
    for (int mt = 0; mt < 4; ++mt) {
      int m = m0 + wm + mt * 16 + lg * 4;
#pragma unroll
      for (int r = 0; r < 4; ++r)
        C[(size_t)(m + r) * 4096 + n] = (f16)(acc[mt][nt][r] + bsum);
    }
  }
}

// ---------------- persistent scan, fence-free coherent barrier --------------
// 128 blocks = 2 streams x 64 unit-groups (16 units each), 1 block/CU, all
// co-resident. Weights in VGPRs. Per step: preload h fragments (coherent
// sc0sc1 dword loads), 64 MFMAs, all-wave LDS reduce (padded), all-thread
// LSTM epilogue (2 cells/thread, dword atomic h store), then flag barrier:
// s_waitcnt vmcnt(0) + relaxed flag store + per-stream poll. No threadfence.
__global__ __launch_bounds__(256, 1) void k_scan(
    const f16* __restrict__ Wp_a, const f16* __restrict__ Wp_m,
    const f16* __restrict__ G_a, const f16* __restrict__ G_m,
    f16* __restrict__ hping,          // 2 x 2 x 32 x 1024, zeroed
    f16* __restrict__ aux_a, f16* __restrict__ aux_m, int aux_ld,
    unsigned* __restrict__ flags) {   // 128 uints, zeroed
  int bi = blockIdx.x;
  int s = bi >> 6, ut = bi & 63, u0 = ut * 16;
  const f16* Wp = s ? Wp_m : Wp_a;
  const f16* G = s ? G_m : G_a;
  f16* aux = s ? aux_m : aux_a;
  int tid = threadIdx.x, l = tid & 63, w = tid >> 6;
  int lr = l & 15, lg = l >> 4;

  // this wave's weight fragments -> registers (held for all 64 steps)
  f16x8 wreg[8][4];
#pragma unroll
  for (int ks = 0; ks < 8; ++ks)
#pragma unroll
    for (int g = 0; g < 4; ++g)
      wreg[ks][g] = *(const f16x8*)(Wp + (size_t)((ut * 4 + g) * 32 + (w * 8 + ks)) * 512 + l * 8);

  __shared__ alignas(16) float red[4][64][33];   // +1 pad: kills 64-way conflict
  __shared__ alignas(16) f16 Gs[32][4][16];

  int pb = tid >> 3, pg = (tid >> 1) & 3, ph = tid & 1;  // G prefetch mapping

  // per-thread cell state: thread owns cells (b_=tid>>3, u=u0+2j, u0+2j+1)
  float creg[2] = {0.f, 0.f};
  int eb = tid >> 3, ej = tid & 7;
  int emt = eb >> 4, elg = (eb >> 2) & 3, er = eb & 3;

  const int S = 2 * 32 * 1024;
  for (int t = 0; t < 64; ++t) {
    const f16* hprev = hping + (t & 1) * S + s * (32 * 1024);
    f16* hnext = hping + ((t & 1) ^ 1) * S + s * (32 * 1024);

    // G t-slice prefetch (plain cached load; read-only data stays in L2)
    f16x8 gfrag = *(const f16x8*)(G + (size_t)(pb * 64 + t) * 4096 + pg * 1024 + u0 + ph * 8);

    // preload all h fragments coherently (pipelined; waitcnt at first use)
    f16x8 a0v[8], a1v[8];
    int kw = w * 256;
#pragma unroll
    for (int ks = 0; ks < 8; ++ks) {
      int kk = kw + ks * 32;
      a0v[ks] = ld_coh16(hprev + lr * 1024 + kk + 8 * lg);
      a1v[ks] = ld_coh16(hprev + (16 + lr) * 1024 + kk + 8 * lg);
    }

    f32x4 acc[2][4];
    f32x4 zero = {0.f, 0.f, 0.f, 0.f};
#pragma unroll
    for (int mt = 0; mt < 2; ++mt)
#pragma unroll
      for (int g = 0; g < 4; ++g) acc[mt][g] = zero;

#pragma unroll
    for (int ks = 0; ks < 8; ++ks) {
#pragma unroll
      for (int g = 0; g < 4; ++g) {
        acc[0][g] = __builtin_amdgcn_mfma_f32_16x16x32_f16(a0v[ks], wreg[ks][g], acc[0][g], 0, 0, 0);
        acc[1][g] = __builtin_amdgcn_mfma_f32_16x16x32_f16(a1v[ks], wreg[ks][g], acc[1][g], 0, 0, 0);
      }
    }

    *(f16x8*)&Gs[pb][pg][ph * 8] = gfrag;
    // all 4 waves write their partial acc
#pragma unroll
    for (int mt = 0; mt < 2; ++mt)
#pragma unroll
      for (int g = 0; g < 4; ++g)
#pragma unroll
        for (int r = 0; r < 4; ++r)
          red[w][l][(mt * 4 + g) * 4 + r] = acc[mt][g][r];
    __syncthreads();

    // all-thread epilogue: 2 adjacent-u cells per thread -> 1 dword store
    {
      f16 hh[2];
#pragma unroll
      for (int cell = 0; cell < 2; ++cell) {
        int row = elg * 16 + 2 * ej + cell;
        float pre[4];
#pragma unroll
        for (int g = 0; g < 4; ++g) {
          int idx = (emt * 4 + g) * 4 + er;
          pre[g] = red[0][row][idx] + red[1][row][idx] + red[2][row][idx] +
                   red[3][row][idx] + (float)Gs[eb][g][2 * ej + cell];
        }
        float cn = sigf(pre[1]) * creg[cell] + sigf(pre[0]) * tanh2(pre[2]);
        creg[cell] = cn;
        hh[cell] = (f16)(sigf(pre[3]) * tanh2(cn));
      }
      union { f16 h[2]; unsigned u; } pk;
      pk.h[0] = hh[0]; pk.h[1] = hh[1];
      int uu = u0 + 2 * ej;
      __hip_atomic_store((unsigned*)(hnext + eb * 1024 + uu), pk.u,
                         __ATOMIC_RELAXED, __HIP_MEMORY_SCOPE_AGENT);
      *(unsigned*)(aux + (size_t)(eb * 64 + t) * aux_ld + uu) = pk.u;
    }

    if (t < 63) {
      // release: drain h stores to coherence point, then set flag (relaxed)
      asm volatile("s_waitcnt vmcnt(0)" ::: "memory");
      if (tid == 0)
        __hip_atomic_store(&flags[bi], (unsigned)(t + 1), __ATOMIC_RELAXED,
                           __HIP_MEMORY_SCOPE_AGENT);
      if (w == 0) {
        unsigned want = (unsigned)(t + 1);
        while (__hip_atomic_load(&flags[s * 64 + l], __ATOMIC_RELAXED,
                                 __HIP_MEMORY_SCOPE_AGENT) < want) {
        }
      }
      __syncthreads();  // also guards LDS WAR for next step
    }
  }
}

// ---------------- fusion: one GEMM phase helper -----------------------------
DEV void gemm_phase(const f16* __restrict__ H, int kA0,
                    const f16* __restrict__ Bp, int brs, int nk,
                    f16* As, f16* Bs, int m0, int n0, int w, int l,
                    int wm, int wn, f32x4 (&acc)[4][2]) {
  f32x4 zero = {0.f, 0.f, 0.f, 0.f};
#pragma unroll
  for (int mt = 0; mt < 4; ++mt)
#pragma unroll
    for (int nt = 0; nt < 2; ++nt) acc[mt][nt] = zero;
  int lr = l & 15, lg = l >> 4;
  int sc = (l & 7) * 8;
  for (int kt = 0; kt < nk; ++kt) {
    int ka = kA0 + kt * 64, kb = kt * 64;
#pragma unroll
    for (int c2 = 0; c2 < 4; ++c2)
      GLDS16(H + (size_t)(m0 + w * 32 + c2 * 8 + (l >> 3)) * 2048 + ka + sc,
             As + (w * 32 + c2 * 8) * 64);
#pragma unroll
    for (int c2 = 0; c2 < 2; ++c2)
      GLDS16(Bp + (size_t)(n0 + w * 16 + c2 * 8 + (l >> 3)) * brs + kb + sc,
             Bs + (w * 16 + c2 * 8) * 64);
    __syncthreads();
#pragma unroll
    for (int ks = 0; ks < 2; ++ks) {
      f16x8 af[4], bf[2];
#pragma unroll
      for (int mt = 0; mt < 4; ++mt)
        af[mt] = *(const f16x8*)&As[(wm + mt * 16 + lr) * 64 + ks * 32 + 8 * lg];
#pragma unroll
      for (int nt = 0; nt < 2; ++nt)
        bf[nt] = *(const f16x8*)&Bs[(wn + nt * 16 + lr) * 64 + ks * 32 + 8 * lg];
#pragma unroll
      for (int mt = 0; mt < 4; ++mt)
#pragma unroll
        for (int nt = 0; nt < 2; ++nt)
          acc[mt][nt] = __builtin_amdgcn_mfma_f32_16x16x32_f16(af[mt], bf[nt], acc[mt][nt], 0, 0, 0);
    }
    __syncthreads();
  }
}

// mem = tm + sig(G)*(ta - tm); 128x64 tile per block, 4 waves of 64x32
__global__ __launch_bounds__(256) void k_fusion(
    const f16* __restrict__ H, const f16* __restrict__ Wg16,
    const f16* __restrict__ Wa16, const f16* __restrict__ Wm16,
    const float* __restrict__ bg, const float* __restrict__ ba,
    const float* __restrict__ bm, float* __restrict__ out) {
  __shared__ alignas(16) f16 As[128 * 64];
  __shared__ alignas(16) f16 Bs[64 * 64];
  int tid = threadIdx.x, l = tid & 63, w = tid >> 6;
  int m0 = blockIdx.x * 128, n0 = blockIdx.y * 64;
  int wm = (w & 1) * 64, wn = (w >> 1) * 32;
  int lr = l & 15, lg = l >> 4;

  f32x4 acc[4][2];
  float ta[4][2][4], tm[4][2][4];

  gemm_phase(H, 0, Wa16, 1024, 16, As, Bs, m0, n0, w, l, wm, wn, acc);
#pragma unroll
  for (int nt = 0; nt < 2; ++nt) {
    float bv = ba[n0 + wn + nt * 16 + lr];
#pragma unroll
    for (int mt = 0; mt < 4; ++mt)
#pragma unroll
      for (int r = 0; r < 4; ++r) ta[mt][nt][r] = tanh2(acc[mt][nt][r] + bv);
  }
  gemm_phase(H, 1024, Wm16, 1024, 16, As, Bs, m0, n0, w, l, wm, wn, acc);
#pragma unroll
  for (int nt = 0; nt < 2; ++nt) {
    float bv = bm[n0 + wn + nt * 16 + lr];
#pragma unroll
    for (int mt = 0; mt < 4; ++mt)
#pragma unroll
      for (int r = 0; r < 4; ++r) tm[mt][nt][r] = tanh2(acc[mt][nt][r] + bv);
  }
  gemm_phase(H, 0, Wg16, 2048, 32, As, Bs, m0, n0, w, l, wm, wn, acc);
#pragma unroll
  for (int nt = 0; nt < 2; ++nt) {
    int n = n0 + wn + nt * 16 + lr;
    float bv = bg[n];
#pragma unroll
    for (int mt = 0; mt < 4; ++mt) {
      int m = m0 + wm + mt * 16 + lg * 4;
#pragma unroll
      for (int r = 0; r < 4; ++r) {
        float g = sigf(acc[mt][nt][r] + bv);
        out[(size_t)(m + r) * 1024 + n] = tm[mt][nt][r] + g * (ta[mt][nt][r] - tm[mt][nt][r]);
      }
    }
  }
}

// ===========================================================================
extern "C" void kernel_launch(void* const* d_in, const int* in_sizes, int n_in,
                              void* d_out, int out_size, void* d_ws, size_t ws_size,
                              hipStream_t stream) {
  const float* xa = (const float*)d_in[0];
  const float* xm = (const float*)d_in[1];
  const float* Wih_1a = (const float*)d_in[2];
  const float* Whh_1a = (const float*)d_in[3];
  const float* bih_1a = (const float*)d_in[4];
  const float* bhh_1a = (const float*)d_in[5];
  const float* Wih_2a = (const float*)d_in[6];
  const float* Whh_2a = (const float*)d_in[7];
  const float* bih_2a = (const float*)d_in[8];
  const float* bhh_2a = (const float*)d_in[9];
  const float* Wih_1m = (const float*)d_in[10];
  const float* Whh_1m = (const float*)d_in[11];
  const float* bih_1m = (const float*)d_in[12];
  const float* bhh_1m = (const float*)d_in[13];
  const float* Wih_2m = (const float*)d_in[14];
  const float* Whh_2m = (const float*)d_in[15];
  const float* bih_2m = (const float*)d_in[16];
  const float* bhh_2m = (const float*)d_in[17];
  const float* Wg = (const float*)d_in[18];
  const float* bg = (const float*)d_in[19];
  const float* Wa = (const float*)d_in[20];
  const float* ba = (const float*)d_in[21];
  const float* Wm = (const float*)d_in[22];
  const float* bm = (const float*)d_in[23];

  char* ws = (char*)d_ws;
  const size_t MB = 1024ull * 1024;
  if (ws_size < 138 * MB) return;  // fail visibly

  // fixed layout (with aliasing; offsets in MB)
  f16* x16a    = (f16*)(ws + 0 * MB);     // dead after GEMM A
  f16* x16m    = (f16*)(ws + 8 * MB);     // dead after GEMM A
  f16* W1ih16a = (f16*)(ws + 16 * MB);    // dead after GEMM A
  f16* W1ih16m = (f16*)(ws + 32 * MB);    // dead after GEMM A
  f16* W2ih16a = (f16*)(ws + 48 * MB);
  f16* W2ih16m = (f16*)(ws + 56 * MB);
  f16* W1p_a   = (f16*)(ws + 64 * MB);
  f16* W1p_m   = (f16*)(ws + 72 * MB);
  f16* W2p_a   = (f16*)(ws + 80 * MB);
  f16* W2p_m   = (f16*)(ws + 88 * MB);
  f16* Wg16    = (f16*)(ws + 96 * MB);
  f16* Wa16    = (f16*)(ws + 100 * MB);
  f16* Wm16    = (f16*)(ws + 102 * MB);
  f16* G0a     = (f16*)(ws + 104 * MB);
  f16* G0m     = (f16*)(ws + 120 * MB);
  f16* hbufA   = (f16*)(ws + 136 * MB);   // 256 KB
  f16* hbufB   = (f16*)(ws + 136 * MB + 256 * 1024);
  unsigned* flagsA = (unsigned*)(ws + 137 * MB);          // 512 B
  unsigned* flagsB = (unsigned*)(ws + 137 * MB + 512);    // 512 B
  // aliases over GEMM-A-dead regions:
  f16* G1a  = (f16*)(ws + 0 * MB);        // 16 MB over x16a+x16m
  f16* G1m  = (f16*)(ws + 16 * MB);       // 16 MB over W1ih16a
  f16* HaHm = (f16*)(ws + 32 * MB);       // 8 MB over W1ih16m[0:8]
  f16* H1a  = (f16*)(ws + 40 * MB);       // 4 MB over W1ih16m[8:12]
  f16* H1m  = (f16*)(ws + 44 * MB);       // 4 MB over W1ih16m[12:16]

  dim3 B256(256);
  k_cvt<<<4096, B256, 0, stream>>>(xa, x16a, 4194304);
  k_cvt<<<4096, B256, 0, stream>>>(xm, x16m, 4194304);
  k_cvt<<<8192, B256, 0, stream>>>(Wih_1a, W1ih16a, 8388608);
  k_cvt<<<8192, B256, 0, stream>>>(Wih_1m, W1ih16m, 8388608);
  k_cvt<<<4096, B256, 0, stream>>>(Wih_2a, W2ih16a, 4194304);
  k_cvt<<<4096, B256, 0, stream>>>(Wih_2m, W2ih16m, 4194304);
  k_cvt<<<2048, B256, 0, stream>>>(Wg, Wg16, 2097152);
  k_cvt<<<1024, B256, 0, stream>>>(Wa, Wa16, 1048576);
  k_cvt<<<1024, B256, 0, stream>>>(Wm, Wm16, 1048576);
  k_packw1<<<2048, B256, 0, stream>>>(Whh_1a, W1p_a);
  k_packw1<<<2048, B256, 0, stream>>>(Whh_1m, W1p_m);
  k_packw1<<<2048, B256, 0, stream>>>(Whh_2a, W2p_a);
  k_packw1<<<2048, B256, 0, stream>>>(Whh_2m, W2p_m);
  hipMemsetAsync(hbufA, 0, 512 * 1024, stream);  // hbufA + hbufB
  hipMemsetAsync(flagsA, 0, 1024, stream);       // flagsA + flagsB

  // GEMM A: G0 = x @ Wih_1^T + (bih_1 + bhh_1)
  k_igemm<32, 2048><<<dim3(16, 32, 2), B256, 0, stream>>>(
      x16a, x16m, W1ih16a, W1ih16m, bih_1a, bhh_1a, bih_1m, bhh_1m, G0a, G0m);

  // persistent scan A: h1 chain -> H1
  k_scan<<<128, B256, 0, stream>>>(W1p_a, W1p_m, G0a, G0m, hbufA, H1a, H1m,
                                   1024, flagsA);

  // GEMM B: G1 = H1 @ Wih_2^T + (bih_2 + bhh_2)
  k_igemm<16, 1024><<<dim3(16, 32, 2), B256, 0, stream>>>(
      H1a, H1m, W2ih16a, W2ih16m, bih_2a, bhh_2a, bih_2m, bhh_2m, G1a, G1m);

  // persistent scan B: h2 chain -> HaHm (a in cols [0,1024), m in [1024,2048))
  k_scan<<<128, B256, 0, stream>>>(W2p_a, W2p_m, G1a, G1m, hbufB, HaHm,
                                   HaHm + 1024, 2048, flagsB);

  k_fusion<<<dim3(16, 16), B256, 0, stream>>>(HaHm, Wg16, Wa16, Wm16, bg, ba,
                                              bm, (float*)d_out);
}

// Round 5
// 1537.770 us; speedup vs baseline: 2.1215x; 1.1434x over previous
//
#include <hip/hip_runtime.h>
#include <cstdint>

typedef _Float16 f16;
typedef _Float16 f16x4v __attribute__((ext_vector_type(4)));
typedef _Float16 f16x8 __attribute__((ext_vector_type(8)));
typedef float f32x4 __attribute__((ext_vector_type(4)));

#define DEV static __device__ __forceinline__

// async global->LDS, 16B per lane; LDS dest = wave-uniform base + lane*16
#define GLDS16(gp, lp) __builtin_amdgcn_global_load_lds( \
    (const __attribute__((address_space(1))) void*)(gp), \
    (__attribute__((address_space(3))) void*)(lp), 16, 0, 0)

DEV float sigf(float x) { return 1.0f / (1.0f + __expf(-x)); }
DEV float tanh2(float x) {
  float e = __expf(-2.0f * fabsf(x));
  float t = (1.0f - e) / (1.0f + e);
  return x >= 0.0f ? t : -t;
}

// coherent (agent-scope, sc0 sc1) 16B load as 4 relaxed dword atomics:
// bypasses potentially-stale L1/L2, reads L3 coherence point, no cache inv.
DEV f16x8 ld_coh16(const f16* p) {
  const unsigned* q = (const unsigned*)p;
  union { unsigned u[4]; f16x8 v; } cv;
#pragma unroll
  for (int i = 0; i < 4; ++i)
    cv.u[i] = __hip_atomic_load(q + i, __ATOMIC_RELAXED, __HIP_MEMORY_SCOPE_AGENT);
  return cv.v;
}

// ---------------- fp32 -> fp16 convert (n % 4 == 0) ----------------
__global__ __launch_bounds__(256) void k_cvt(const float* __restrict__ s,
                                             f16* __restrict__ d, int n) {
  int i = (blockIdx.x * 256 + threadIdx.x) * 4;
  if (i >= n) return;
  float4 v = *(const float4*)(s + i);
  f16x4v o;
  o.x = (f16)v.x; o.y = (f16)v.y; o.z = (f16)v.z; o.w = (f16)v.w;
  *(f16x4v*)(d + i) = o;
}

// ---------------- pack Whh (4096x1024 fp32) into MFMA fragment order -------
// frag = (ut*4+gate)*32 + kt ; lane l holds 8 halves =
// W[gate*1024 + ut*16 + (l&15)][kt*32 + 8*(l>>4) + j]
__global__ __launch_bounds__(256) void k_packw1(const float* __restrict__ W,
                                                f16* __restrict__ P) {
  int i2 = blockIdx.x * 256 + threadIdx.x;   // 0 .. 524287
  int l = i2 & 63, frag = i2 >> 6;
  int kt = frag & 31, ug = frag >> 5;
  int gate = ug & 3, ut = ug >> 2;
  int row = gate * 1024 + ut * 16 + (l & 15);
  int k = kt * 32 + 8 * (l >> 4);
  const float* s = W + row * 1024 + k;
  f16x8 o;
#pragma unroll
  for (int j = 0; j < 8; ++j) o[j] = (f16)s[j];
  *(f16x8*)(P + frag * 512 + l * 8) = o;
}

// ---------------- big GEMM: C = A @ B^T + (bi+bh), fp16 out ----------------
template <int NKT, int LDA>
__global__ __launch_bounds__(256) void k_igemm(
    const f16* __restrict__ A0, const f16* __restrict__ A1,
    const f16* __restrict__ B0, const f16* __restrict__ B1,
    const float* __restrict__ bi0, const float* __restrict__ bh0,
    const float* __restrict__ bi1, const float* __restrict__ bh1,
    f16* __restrict__ C0, f16* __restrict__ C1) {
  const f16* A = blockIdx.z ? A1 : A0;
  const f16* B = blockIdx.z ? B1 : B0;
  const float* bi = blockIdx.z ? bi1 : bi0;
  const float* bh = blockIdx.z ? bh1 : bh0;
  f16* C = blockIdx.z ? C1 : C0;

  __shared__ alignas(16) f16 As[128 * 64];
  __shared__ alignas(16) f16 Bs[128 * 64];

  int tid = threadIdx.x, l = tid & 63, w = tid >> 6;
  int m0 = blockIdx.x * 128, n0 = blockIdx.y * 128;
  int wm = (w & 1) * 64, wn = (w >> 1) * 64;
  int lr = l & 15, lg = l >> 4;
  int sr = w * 32 + (l >> 3);
  int sc = (l & 7) * 8;

  f32x4 acc[4][4];
  f32x4 zero = {0.f, 0.f, 0.f, 0.f};
#pragma unroll
  for (int mt = 0; mt < 4; ++mt)
#pragma unroll
    for (int nt = 0; nt < 4; ++nt) acc[mt][nt] = zero;

  for (int kt = 0; kt < NKT; ++kt) {
    int k0 = kt * 64;
#pragma unroll
    for (int c2 = 0; c2 < 4; ++c2) {
      GLDS16(A + (size_t)(m0 + sr + c2 * 8) * LDA + k0 + sc, &As[(w * 32 + c2 * 8) * 64]);
      GLDS16(B + (size_t)(n0 + sr + c2 * 8) * LDA + k0 + sc, &Bs[(w * 32 + c2 * 8) * 64]);
    }
    __syncthreads();
#pragma unroll
    for (int ks = 0; ks < 2; ++ks) {
      f16x8 af[4], bf[4];
#pragma unroll
      for (int mt = 0; mt < 4; ++mt)
        af[mt] = *(const f16x8*)&As[(wm + mt * 16 + lr) * 64 + ks * 32 + 8 * lg];
#pragma unroll
      for (int nt = 0; nt < 4; ++nt)
        bf[nt] = *(const f16x8*)&Bs[(wn + nt * 16 + lr) * 64 + ks * 32 + 8 * lg];
#pragma unroll
      for (int mt = 0; mt < 4; ++mt)
#pragma unroll
        for (int nt = 0; nt < 4; ++nt)
          acc[mt][nt] = __builtin_amdgcn_mfma_f32_16x16x32_f16(af[mt], bf[nt], acc[mt][nt], 0, 0, 0);
    }
    __syncthreads();
  }

#pragma unroll
  for (int nt = 0; nt < 4; ++nt) {
    int n = n0 + wn + nt * 16 + lr;
    float bsum = bi[n] + bh[n];
#pragma unroll
    for (int mt = 0; mt < 4; ++mt) {
      int m = m0 + wm + mt * 16 + lg * 4;
#pragma unroll
      for (int r = 0; r < 4; ++r)
        C[(size_t)(m + r) * 4096 + n] = (f16)(acc[mt][nt][r] + bsum);
    }
  }
}

// ---------------- persistent scan, pinned weights + counter-tree barrier ----
// 128 blocks = 2 streams x 64 unit-groups (16 units each), 1 block/CU, all
// co-resident. Weights PINNED in VGPRs via opaque asm (compiler cannot
// rematerialize the loads inside the loop). Barrier: 8 counters/stream
// (64 B apart), arrival = 1 atomicAdd from tid0, poll = lanes 0..7 only.
__global__ __launch_bounds__(256, 1) void k_scan(
    const f16* __restrict__ Wp_a, const f16* __restrict__ Wp_m,
    const f16* __restrict__ G_a, const f16* __restrict__ G_m,
    f16* __restrict__ hping,          // 2 x 2 x 32 x 1024, zeroed
    f16* __restrict__ aux_a, f16* __restrict__ aux_m, int aux_ld,
    unsigned* __restrict__ cnt) {     // 16 counters x 16-dword spacing, zeroed
  int bi = blockIdx.x;
  int s = bi >> 6, ut = bi & 63, u0 = ut * 16;
  const f16* Wp = s ? Wp_m : Wp_a;
  const f16* G = s ? G_m : G_a;
  f16* aux = s ? aux_m : aux_a;
  int tid = threadIdx.x, l = tid & 63, w = tid >> 6;
  int lr = l & 15, lg = l >> 4;

  // this wave's weight fragments -> registers, PINNED for all 64 steps
  f16x8 wreg[8][4];
#pragma unroll
  for (int ks = 0; ks < 8; ++ks)
#pragma unroll
    for (int g = 0; g < 4; ++g)
      wreg[ks][g] = *(const f16x8*)(Wp + (size_t)((ut * 4 + g) * 32 + (w * 8 + ks)) * 512 + l * 8);
#pragma unroll
  for (int ks = 0; ks < 8; ++ks)
#pragma unroll
    for (int g = 0; g < 4; ++g)
      asm volatile("" : "+v"(wreg[ks][g]));   // opaque: forces VGPR residency

  __shared__ alignas(16) float red[4][64][33];   // +1 pad: kills 64-way conflict
  __shared__ alignas(16) f16 Gs[32][4][16];

  int pb = tid >> 3, pg = (tid >> 1) & 3, ph = tid & 1;  // G prefetch mapping

  // per-thread cell state: thread owns cells (b_=tid>>3, u=u0+2j, u0+2j+1)
  float creg[2] = {0.f, 0.f};
  int eb = tid >> 3, ej = tid & 7;
  int emt = eb >> 4, elg = (eb >> 2) & 3, er = eb & 3;

  const int S = 2 * 32 * 1024;
  for (int t = 0; t < 64; ++t) {
    const f16* hprev = hping + (t & 1) * S + s * (32 * 1024);
    f16* hnext = hping + ((t & 1) ^ 1) * S + s * (32 * 1024);

    // G t-slice prefetch (plain cached load; read-only data stays in L2)
    f16x8 gfrag = *(const f16x8*)(G + (size_t)(pb * 64 + t) * 4096 + pg * 1024 + u0 + ph * 8);

    // preload all h fragments coherently (pipelined; waitcnt at first use)
    f16x8 a0v[8], a1v[8];
    int kw = w * 256;
#pragma unroll
    for (int ks = 0; ks < 8; ++ks) {
      int kk = kw + ks * 32;
      a0v[ks] = ld_coh16(hprev + lr * 1024 + kk + 8 * lg);
      a1v[ks] = ld_coh16(hprev + (16 + lr) * 1024 + kk + 8 * lg);
    }

    f32x4 acc[2][4];
    f32x4 zero = {0.f, 0.f, 0.f, 0.f};
#pragma unroll
    for (int mt = 0; mt < 2; ++mt)
#pragma unroll
      for (int g = 0; g < 4; ++g) acc[mt][g] = zero;

#pragma unroll
    for (int ks = 0; ks < 8; ++ks) {
#pragma unroll
      for (int g = 0; g < 4; ++g) {
        acc[0][g] = __builtin_amdgcn_mfma_f32_16x16x32_f16(a0v[ks], wreg[ks][g], acc[0][g], 0, 0, 0);
        acc[1][g] = __builtin_amdgcn_mfma_f32_16x16x32_f16(a1v[ks], wreg[ks][g], acc[1][g], 0, 0, 0);
      }
    }

    *(f16x8*)&Gs[pb][pg][ph * 8] = gfrag;
    // all 4 waves write their partial acc
#pragma unroll
    for (int mt = 0; mt < 2; ++mt)
#pragma unroll
      for (int g = 0; g < 4; ++g)
#pragma unroll
        for (int r = 0; r < 4; ++r)
          red[w][l][(mt * 4 + g) * 4 + r] = acc[mt][g][r];
    __syncthreads();

    // all-thread epilogue: 2 adjacent-u cells per thread -> 1 dword store
    {
      f16 hh[2];
#pragma unroll
      for (int cell = 0; cell < 2; ++cell) {
        int row = elg * 16 + 2 * ej + cell;
        float pre[4];
#pragma unroll
        for (int g = 0; g < 4; ++g) {
          int idx = (emt * 4 + g) * 4 + er;
          pre[g] = red[0][row][idx] + red[1][row][idx] + red[2][row][idx] +
                   red[3][row][idx] + (float)Gs[eb][g][2 * ej + cell];
        }
        float cn = sigf(pre[1]) * creg[cell] + sigf(pre[0]) * tanh2(pre[2]);
        creg[cell] = cn;
        hh[cell] = (f16)(sigf(pre[3]) * tanh2(cn));
      }
      union { f16 h[2]; unsigned u; } pk;
      pk.h[0] = hh[0]; pk.h[1] = hh[1];
      int uu = u0 + 2 * ej;
      // h store FIRST (must be oldest outstanding for vmcnt(1) release)
      __hip_atomic_store((unsigned*)(hnext + eb * 1024 + uu), pk.u,
                         __ATOMIC_RELAXED, __HIP_MEMORY_SCOPE_AGENT);
      asm volatile("" ::: "memory");   // keep aux store AFTER h store
      *(unsigned*)(aux + (size_t)(eb * 64 + t) * aux_ld + uu) = pk.u;
    }

    if (t < 63) {
      // release: wait only for the h store (oldest); aux ack may be pending
      asm volatile("s_waitcnt vmcnt(1)" ::: "memory");
      if (tid == 0)
        __hip_atomic_fetch_add(&cnt[(s * 8 + (bi & 7)) * 16], 1u,
                               __ATOMIC_RELAXED, __HIP_MEMORY_SCOPE_AGENT);
      if (tid < 8) {
        unsigned want = 8u * (unsigned)(t + 1);
        while (__hip_atomic_load(&cnt[(s * 8 + tid) * 16], __ATOMIC_RELAXED,
                                 __HIP_MEMORY_SCOPE_AGENT) < want) {
        }
      }
      __syncthreads();  // also guards LDS WAR for next step
    }
  }
}

// ---------------- fusion: one GEMM phase helper -----------------------------
DEV void gemm_phase(const f16* __restrict__ H, int kA0,
                    const f16* __restrict__ Bp, int brs, int nk,
                    f16* As, f16* Bs, int m0, int n0, int w, int l,
                    int wm, int wn, f32x4 (&acc)[4][2]) {
  f32x4 zero = {0.f, 0.f, 0.f, 0.f};
#pragma unroll
  for (int mt = 0; mt < 4; ++mt)
#pragma unroll
    for (int nt = 0; nt < 2; ++nt) acc[mt][nt] = zero;
  int lr = l & 15, lg = l >> 4;
  int sc = (l & 7) * 8;
  for (int kt = 0; kt < nk; ++kt) {
    int ka = kA0 + kt * 64, kb = kt * 64;
#pragma unroll
    for (int c2 = 0; c2 < 4; ++c2)
      GLDS16(H + (size_t)(m0 + w * 32 + c2 * 8 + (l >> 3)) * 2048 + ka + sc,
             As + (w * 32 + c2 * 8) * 64);
#pragma unroll
    for (int c2 = 0; c2 < 2; ++c2)
      GLDS16(Bp + (size_t)(n0 + w * 16 + c2 * 8 + (l >> 3)) * brs + kb + sc,
             Bs + (w * 16 + c2 * 8) * 64);
    __syncthreads();
#pragma unroll
    for (int ks = 0; ks < 2; ++ks) {
      f16x8 af[4], bf[2];
#pragma unroll
      for (int mt = 0; mt < 4; ++mt)
        af[mt] = *(const f16x8*)&As[(wm + mt * 16 + lr) * 64 + ks * 32 + 8 * lg];
#pragma unroll
      for (int nt = 0; nt < 2; ++nt)
        bf[nt] = *(const f16x8*)&Bs[(wn + nt * 16 + lr) * 64 + ks * 32 + 8 * lg];
#pragma unroll
      for (int mt = 0; mt < 4; ++mt)
#pragma unroll
        for (int nt = 0; nt < 2; ++nt)
          acc[mt][nt] = __builtin_amdgcn_mfma_f32_16x16x32_f16(af[mt], bf[nt], acc[mt][nt], 0, 0, 0);
    }
    __syncthreads();
  }
}

// mem = tm + sig(G)*(ta - tm); 128x64 tile per block, 4 waves of 64x32
__global__ __launch_bounds__(256) void k_fusion(
    const f16* __restrict__ H, const f16* __restrict__ Wg16,
    const f16* __restrict__ Wa16, const f16* __restrict__ Wm16,
    const float* __restrict__ bg, const float* __restrict__ ba,
    const float* __restrict__ bm, float* __restrict__ out) {
  __shared__ alignas(16) f16 As[128 * 64];
  __shared__ alignas(16) f16 Bs[64 * 64];
  int tid = threadIdx.x, l = tid & 63, w = tid >> 6;
  int m0 = blockIdx.x * 128, n0 = blockIdx.y * 64;
  int wm = (w & 1) * 64, wn = (w >> 1) * 32;
  int lr = l & 15, lg = l >> 4;

  f32x4 acc[4][2];
  float ta[4][2][4], tm[4][2][4];

  gemm_phase(H, 0, Wa16, 1024, 16, As, Bs, m0, n0, w, l, wm, wn, acc);
#pragma unroll
  for (int nt = 0; nt < 2; ++nt) {
    float bv = ba[n0 + wn + nt * 16 + lr];
#pragma unroll
    for (int mt = 0; mt < 4; ++mt)
#pragma unroll
      for (int r = 0; r < 4; ++r) ta[mt][nt][r] = tanh2(acc[mt][nt][r] + bv);
  }
  gemm_phase(H, 1024, Wm16, 1024, 16, As, Bs, m0, n0, w, l, wm, wn, acc);
#pragma unroll
  for (int nt = 0; nt < 2; ++nt) {
    float bv = bm[n0 + wn + nt * 16 + lr];
#pragma unroll
    for (int mt = 0; mt < 4; ++mt)
#pragma unroll
      for (int r = 0; r < 4; ++r) tm[mt][nt][r] = tanh2(acc[mt][nt][r] + bv);
  }
  gemm_phase(H, 0, Wg16, 2048, 32, As, Bs, m0, n0, w, l, wm, wn, acc);
#pragma unroll
  for (int nt = 0; nt < 2; ++nt) {
    int n = n0 + wn + nt * 16 + lr;
    float bv = bg[n];
#pragma unroll
    for (int mt = 0; mt < 4; ++mt) {
      int m = m0 + wm + mt * 16 + lg * 4;
#pragma unroll
      for (int r = 0; r < 4; ++r) {
        float g = sigf(acc[mt][nt][r] + bv);
        out[(size_t)(m + r) * 1024 + n] = tm[mt][nt][r] + g * (ta[mt][nt][r] - tm[mt][nt][r]);
      }
    }
  }
}

// ===========================================================================
extern "C" void kernel_launch(void* const* d_in, const int* in_sizes, int n_in,
                              void* d_out, int out_size, void* d_ws, size_t ws_size,
                              hipStream_t stream) {
  const float* xa = (const float*)d_in[0];
  const float* xm = (const float*)d_in[1];
  const float* Wih_1a = (const float*)d_in[2];
  const float* Whh_1a = (const float*)d_in[3];
  const float* bih_1a = (const float*)d_in[4];
  const float* bhh_1a = (const float*)d_in[5];
  const float* Wih_2a = (const float*)d_in[6];
  const float* Whh_2a = (const float*)d_in[7];
  const float* bih_2a = (const float*)d_in[8];
  const float* bhh_2a = (const float*)d_in[9];
  const float* Wih_1m = (const float*)d_in[10];
  const float* Whh_1m = (const float*)d_in[11];
  const float* bih_1m = (const float*)d_in[12];
  const float* bhh_1m = (const float*)d_in[13];
  const float* Wih_2m = (const float*)d_in[14];
  const float* Whh_2m = (const float*)d_in[15];
  const float* bih_2m = (const float*)d_in[16];
  const float* bhh_2m = (const float*)d_in[17];
  const float* Wg = (const float*)d_in[18];
  const float* bg = (const float*)d_in[19];
  const float* Wa = (const float*)d_in[20];
  const float* ba = (const float*)d_in[21];
  const float* Wm = (const float*)d_in[22];
  const float* bm = (const float*)d_in[23];

  char* ws = (char*)d_ws;
  const size_t MB = 1024ull * 1024;
  if (ws_size < 138 * MB) return;  // fail visibly

  // fixed layout (with aliasing; offsets in MB)
  f16* x16a    = (f16*)(ws + 0 * MB);     // dead after GEMM A
  f16* x16m    = (f16*)(ws + 8 * MB);     // dead after GEMM A
  f16* W1ih16a = (f16*)(ws + 16 * MB);    // dead after GEMM A
  f16* W1ih16m = (f16*)(ws + 32 * MB);    // dead after GEMM A
  f16* W2ih16a = (f16*)(ws + 48 * MB);
  f16* W2ih16m = (f16*)(ws + 56 * MB);
  f16* W1p_a   = (f16*)(ws + 64 * MB);
  f16* W1p_m   = (f16*)(ws + 72 * MB);
  f16* W2p_a   = (f16*)(ws + 80 * MB);
  f16* W2p_m   = (f16*)(ws + 88 * MB);
  f16* Wg16    = (f16*)(ws + 96 * MB);
  f16* Wa16    = (f16*)(ws + 100 * MB);
  f16* Wm16    = (f16*)(ws + 102 * MB);
  f16* G0a     = (f16*)(ws + 104 * MB);
  f16* G0m     = (f16*)(ws + 120 * MB);
  f16* hbufA   = (f16*)(ws + 136 * MB);   // 256 KB
  f16* hbufB   = (f16*)(ws + 136 * MB + 256 * 1024);
  unsigned* cntA = (unsigned*)(ws + 137 * MB);          // 16 ctr x 64 B = 1 KB
  unsigned* cntB = (unsigned*)(ws + 137 * MB + 1024);   // 1 KB
  // aliases over GEMM-A-dead regions:
  f16* G1a  = (f16*)(ws + 0 * MB);        // 16 MB over x16a+x16m
  f16* G1m  = (f16*)(ws + 16 * MB);       // 16 MB over W1ih16a
  f16* HaHm = (f16*)(ws + 32 * MB);       // 8 MB over W1ih16m[0:8]
  f16* H1a  = (f16*)(ws + 40 * MB);       // 4 MB over W1ih16m[8:12]
  f16* H1m  = (f16*)(ws + 44 * MB);       // 4 MB over W1ih16m[12:16]

  dim3 B256(256);
  k_cvt<<<4096, B256, 0, stream>>>(xa, x16a, 4194304);
  k_cvt<<<4096, B256, 0, stream>>>(xm, x16m, 4194304);
  k_cvt<<<8192, B256, 0, stream>>>(Wih_1a, W1ih16a, 8388608);
  k_cvt<<<8192, B256, 0, stream>>>(Wih_1m, W1ih16m, 8388608);
  k_cvt<<<4096, B256, 0, stream>>>(Wih_2a, W2ih16a, 4194304);
  k_cvt<<<4096, B256, 0, stream>>>(Wih_2m, W2ih16m, 4194304);
  k_cvt<<<2048, B256, 0, stream>>>(Wg, Wg16, 2097152);
  k_cvt<<<1024, B256, 0, stream>>>(Wa, Wa16, 1048576);
  k_cvt<<<1024, B256, 0, stream>>>(Wm, Wm16, 1048576);
  k_packw1<<<2048, B256, 0, stream>>>(Whh_1a, W1p_a);
  k_packw1<<<2048, B256, 0, stream>>>(Whh_1m, W1p_m);
  k_packw1<<<2048, B256, 0, stream>>>(Whh_2a, W2p_a);
  k_packw1<<<2048, B256, 0, stream>>>(Whh_2m, W2p_m);
  hipMemsetAsync(hbufA, 0, 512 * 1024, stream);  // hbufA + hbufB
  hipMemsetAsync(cntA, 0, 2048, stream);         // cntA + cntB

  // GEMM A: G0 = x @ Wih_1^T + (bih_1 + bhh_1)
  k_igemm<32, 2048><<<dim3(16, 32, 2), B256, 0, stream>>>(
      x16a, x16m, W1ih16a, W1ih16m, bih_1a, bhh_1a, bih_1m, bhh_1m, G0a, G0m);

  // persistent scan A: h1 chain -> H1
  k_scan<<<128, B256, 0, stream>>>(W1p_a, W1p_m, G0a, G0m, hbufA, H1a, H1m,
                                   1024, cntA);

  // GEMM B: G1 = H1 @ Wih_2^T + (bih_2 + bhh_2)
  k_igemm<16, 1024><<<dim3(16, 32, 2), B256, 0, stream>>>(
      H1a, H1m, W2ih16a, W2ih16m, bih_2a, bhh_2a, bih_2m, bhh_2m, G1a, G1m);

  // persistent scan B: h2 chain -> HaHm (a in cols [0,1024), m in [1024,2048))
  k_scan<<<128, B256, 0, stream>>>(W2p_a, W2p_m, G1a, G1m, hbufB, HaHm,
                                   HaHm + 1024, 2048, cntB);

  k_fusion<<<dim3(16, 16), B256, 0, stream>>>(HaHm, Wg16, Wa16, Wm16, bg, ba,
                                              bm, (float*)d_out);
}